// Round 4
// baseline (1858.527 us; speedup 1.0000x reference)
//
#include <hip/hip_runtime.h>
#include <math.h>

// Problem constants
#define NN    8
#define CC_   96
#define HH    56
#define WW    56
#define HWHW  (HH*WW)            // 3136
#define NPIX  (NN*HWHW)          // 25088
#define NELEM (NN*CC_*HWHW)      // 2408448
#define GROUPS 4
#define IG    24                 // channels per group
#define KTAP  216                // 24*9
#define NITER 25
#define EPSV  1e-12f

// Packed weight chunk: per (g,ocg,ic) 9 taps x 6 oc = 54 floats, padded to 56.
#define WCHUNK 56
#define WTOTAL (GROUPS*4*IG*WCHUNK)   // 21504

typedef float sf16 __attribute__((ext_vector_type(16)));
typedef float sf8  __attribute__((ext_vector_type(8)));

// ---------------------------------------------------------------------------
// Normalize weights and pack into BOTH conv layouts (see round 2 comments).
__global__ void wnorm2_kernel(const float* __restrict__ w_in,
                              float* __restrict__ Wf, float* __restrict__ Wt) {
    int o = blockIdx.x;          // 96
    int t = threadIdx.x;         // 256
    float myv = (t < KTAP) ? fabsf(w_in[o*KTAP + t]) : 0.f;
    float v = myv;
    #pragma unroll
    for (int off = 32; off; off >>= 1) v += __shfl_down(v, off, 64);
    __shared__ float red[4];
    if ((t & 63) == 0) red[t >> 6] = v;
    __syncthreads();
    float s = red[0] + red[1] + red[2] + red[3];
    if (t < KTAP) {
        float w = myv / (s + EPSV);
        int ic = t / 9, k = t % 9;
        int g  = o / IG, ol = o % IG;
        Wf[((g*4 + ol/6)*IG + ic)*WCHUNK + k*6 + (ol%6)] = w;
        Wt[((g*4 + ic/6)*IG + ol)*WCHUNK + (8-k)*6 + (ic%6)] = w;
    }
}

// ---------------------------------------------------------------------------
// LN (channels-first, eps 1e-6) -> relu -> x / (sum_c x + EPS)  => X
__global__ void ln1_kernel(const float* __restrict__ x, const float* __restrict__ lw,
                           const float* __restrict__ lb, float* __restrict__ X) {
    int p = blockIdx.x * blockDim.x + threadIdx.x;
    if (p >= NPIX) return;
    int n = p / HWHW, hw = p % HWHW;
    const float* xp = x + (size_t)n*CC_*HWHW + hw;
    float s = 0.f, ss = 0.f;
    for (int c = 0; c < CC_; ++c) { float v = xp[(size_t)c*HWHW]; s += v; ss += v*v; }
    float u  = s * (1.f/CC_);
    float var = ss * (1.f/CC_) - u*u;
    float rs = rsqrtf(var + 1e-6f);
    float sr = 0.f;
    for (int c = 0; c < CC_; ++c) {
        float v = xp[(size_t)c*HWHW];
        float a = fmaxf((v-u)*rs*lw[c] + lb[c], 0.f);
        sr += a;
    }
    float inv = 1.f / (sr + EPSV);
    float* Xp = X + (size_t)n*CC_*HWHW + hw;
    for (int c = 0; c < CC_; ++c) {
        float v = xp[(size_t)c*HWHW];
        float a = fmaxf((v-u)*rs*lw[c] + lb[c], 0.f);
        Xp[(size_t)c*HWHW] = a * inv;
    }
}

// ---------------------------------------------------------------------------
__global__ void fill_kernel(float* __restrict__ p, int n, float v) {
    int i = blockIdx.x * blockDim.x + threadIdx.x;
    if (i < n) p[i] = v;
}

// ---------------------------------------------------------------------------
// Grouped 3x3 conv (pad 1), 24->24 per group.
// Block: 256 thr = 4 waves, wave = ocg (6 oc). Lane<56: row=lane/14, 4 px.
// Weights: wave-uniform s_load into SGPRs (no VMEM, no LDS).
// EPI==0 (convT / ratio): stages Hu/(Scur+EPS); zeroes Snxt slice; out = X/(acc+EPS)
// EPI==1 (mult update):   stages R raw; h = Hu/(Scur+EPS)*acc; Hu=h; Snxt += sum_c h
template<int EPI>
__global__ __launch_bounds__(256, 4) void conv4_kernel(const float* __restrict__ in,
                                                       const float* __restrict__ W,
                                                       const float* __restrict__ X,
                                                       const float* __restrict__ Scur,
                                                       float* __restrict__ Snxt,
                                                       float* __restrict__ Hu,
                                                       float* __restrict__ out) {
    __shared__ float lin[IG*6*60];      // [ic][6 rows][60 (58 used)] 34.6 KB
    int b   = blockIdx.x;               // 8*4*14 = 448
    int rt  = b % 14;
    int g   = (b / 14) % GROUPS;
    int n   = b / 56;
    int tid = threadIdx.x;

    if (EPI == 0) {   // zero next-S (448*56 == 25088)
        if (tid < 56) Snxt[b*56 + tid] = 0.f;
    }

    // stage input tile: rows rt*4-1 .. rt*4+4 (6), cols -1..56 stored at 0..57
    const float* inb = in + ((size_t)n*CC_ + g*IG) * HWHW;
    const float* Sb  = Scur + n*HWHW;
    int r0 = rt*4 - 1;
    for (int idx = tid; idx < IG*6*58; idx += 256) {
        int ic  = idx / 348;
        int rem = idx % 348;
        int r   = rem / 58, pos = rem % 58;
        int gr = r0 + r, gc = pos - 1;
        float v = 0.f;
        if (gr >= 0 && gr < HH && gc >= 0 && gc < WW) {
            v = inb[(size_t)ic*HWHW + gr*WW + gc];
            if (EPI == 0) v = v / (Sb[gr*WW + gc] + EPSV);
        }
        lin[ic*360 + r*60 + pos] = v;
    }
    __syncthreads();

    int ocg  = __builtin_amdgcn_readfirstlane(tid >> 6);   // 0..3, uniform
    int lane = tid & 63;
    if (lane >= 56) return;
    int xt  = lane % 14;
    int row = lane / 14;                 // 0..3
    int x0  = xt * 4;

    const float* Wc = W + (size_t)((g*4 + ocg)*IG) * WCHUNK;   // uniform (SGPR)

    float acc[6][4] = {};
    #pragma unroll 1
    for (int ic = 0; ic < IG; ++ic) {
        sf16 wa, wb, wc2; sf8 wd;
        const float* Wic = Wc + ic*WCHUNK;
        asm volatile(
            "s_load_dwordx16 %0, %4, 0x0\n\t"
            "s_load_dwordx16 %1, %4, 0x40\n\t"
            "s_load_dwordx16 %2, %4, 0x80\n\t"
            "s_load_dwordx8  %3, %4, 0xc0\n\t"
            "s_waitcnt lgkmcnt(0)"
            : "=&s"(wa), "=&s"(wb), "=&s"(wc2), "=&s"(wd)
            : "s"(Wic));
        #define WF(i) ((i)<16 ? wa[(i)] : (i)<32 ? wb[(i)-16] : (i)<48 ? wc2[(i)-32] : wd[(i)-48])

        const float* lb = &lin[ic*360 + row*60 + x0];
        float v[3][6];
        #pragma unroll
        for (int ky = 0; ky < 3; ++ky) {
            float4 a = *(const float4*)(lb + ky*60);
            float2 c2 = *(const float2*)(lb + ky*60 + 4);
            v[ky][0]=a.x; v[ky][1]=a.y; v[ky][2]=a.z; v[ky][3]=a.w;
            v[ky][4]=c2.x; v[ky][5]=c2.y;
        }
        #pragma unroll
        for (int ky = 0; ky < 3; ++ky)
            #pragma unroll
            for (int kx = 0; kx < 3; ++kx) {
                const int tap = ky*3 + kx;
                #pragma unroll
                for (int o = 0; o < 6; ++o) {
                    float wv = WF(tap*6 + o);
                    #pragma unroll
                    for (int p = 0; p < 4; ++p)
                        acc[o][p] = fmaf(v[ky][kx+p], wv, acc[o][p]);
                }
            }
        #undef WF
    }

    int grow = rt*4 + row;
    size_t obase = ((size_t)n*CC_ + g*IG + ocg*6) * HWHW + grow*WW + x0;

    if (EPI == 0) {
        #pragma unroll
        for (int o = 0; o < 6; ++o) {
            size_t bo = obase + (size_t)o*HWHW;
            float4 xx = *(const float4*)(X + bo);
            float4 r;
            r.x = xx.x / (acc[o][0] + EPSV);
            r.y = xx.y / (acc[o][1] + EPSV);
            r.z = xx.z / (acc[o][2] + EPSV);
            r.w = xx.w / (acc[o][3] + EPSV);
            *(float4*)(out + bo) = r;
        }
    } else {
        int pix = n*HWHW + grow*WW + x0;
        float4 sv = *(const float4*)(Scur + pix);
        float i0 = 1.f/(sv.x+EPSV), i1 = 1.f/(sv.y+EPSV);
        float i2 = 1.f/(sv.z+EPSV), i3 = 1.f/(sv.w+EPSV);
        float ps0=0.f, ps1=0.f, ps2=0.f, ps3=0.f;
        #pragma unroll
        for (int o = 0; o < 6; ++o) {
            size_t bo = obase + (size_t)o*HWHW;
            float4 hu = *(const float4*)(Hu + bo);
            float4 h;
            h.x = hu.x * i0 * acc[o][0];
            h.y = hu.y * i1 * acc[o][1];
            h.z = hu.z * i2 * acc[o][2];
            h.w = hu.w * i3 * acc[o][3];
            *(float4*)(Hu + bo) = h;
            ps0 += h.x; ps1 += h.y; ps2 += h.z; ps3 += h.w;
        }
        atomicAdd(&Snxt[pix+0], ps0);
        atomicAdd(&Snxt[pix+1], ps1);
        atomicAdd(&Snxt[pix+2], ps2);
        atomicAdd(&Snxt[pix+3], ps3);
    }
}

// ---------------------------------------------------------------------------
// x2 = x + Hu/(S+EPS) -> d_out ; XLN = LN(x2) (over C, eps 1e-5) -> R
__global__ void resln2_kernel(const float* __restrict__ x, const float* __restrict__ Hu,
                              const float* __restrict__ S,
                              const float* __restrict__ lw, const float* __restrict__ lb,
                              float* __restrict__ out, float* __restrict__ XLN) {
    int p = blockIdx.x * blockDim.x + threadIdx.x;
    if (p >= NPIX) return;
    int n = p / HWHW, hw = p % HWHW;
    size_t base = (size_t)n*CC_*HWHW + hw;
    float sinv = 1.f / (S[p] + EPSV);
    float s = 0.f, ss = 0.f;
    for (int c = 0; c < CC_; ++c) {
        float v = x[base + (size_t)c*HWHW] + Hu[base + (size_t)c*HWHW] * sinv;
        out[base + (size_t)c*HWHW] = v;
        s += v; ss += v*v;
    }
    float u  = s * (1.f/CC_);
    float var = ss * (1.f/CC_) - u*u;
    float rs = rsqrtf(var + 1e-5f);
    for (int c = 0; c < CC_; ++c) {
        float v = out[base + (size_t)c*HWHW];
        XLN[base + (size_t)c*HWHW] = (v-u)*rs*lw[c] + lb[c];
    }
}

// ---------------------------------------------------------------------------
// Fused MLP: out += gelu(XLN @ w1 + b1) @ w2 + b2.  32 tokens/block, 384 thr.
// lx[c*32+t] (12.3 KB); lh[j*32 + swizzled t-chunk] (49.2 KB).
// gemm1: tile 4t x 8j (tid = tg*48+jg). gemm2: k-split 4, tile 4t x 8c
// (tid = kq*96 + cg*8 + tg). Partials reduced through the lh region.
__global__ __launch_bounds__(384, 3) void mlp3_kernel(const float* __restrict__ XLN,
                                                      const float* __restrict__ w1,
                                                      const float* __restrict__ b1,
                                                      const float* __restrict__ w2,
                                                      const float* __restrict__ b2,
                                                      float* __restrict__ out) {
    __shared__ float lx[CC_*32];         // 12288 B
    __shared__ float lh[384*32];         // 49152 B (also reused for partials)
    int blk = blockIdx.x;                // 784
    int tid = threadIdx.x;               // 384
    int p0  = blk * 32;
    int n   = p0 / HWHW;
    int hw0 = p0 % HWHW;
    const float* Xb = XLN + (size_t)n*CC_*HWHW + hw0;
    for (int idx = tid; idx < CC_*32; idx += 384) {
        int c = idx >> 5, t = idx & 31;
        lx[c*32 + t] = Xb[(size_t)c*HWHW + t];
    }
    __syncthreads();

    // ---- GEMM1: [32 x 96] @ [96 x 384]
    {
        int tg = tid / 48, jg = tid % 48;    // t0 = tg*4, j0 = jg*8
        int t0 = tg*4, j0 = jg*8;
        float acc1[4][8] = {};
        for (int k = 0; k < CC_; ++k) {
            float4 a  = *(const float4*)&lx[k*32 + t0];
            float4 wA = *(const float4*)&w1[(size_t)k*384 + j0];
            float4 wB = *(const float4*)&w1[(size_t)k*384 + j0 + 4];
            float wv[8] = {wA.x,wA.y,wA.z,wA.w,wB.x,wB.y,wB.z,wB.w};
            float av[4] = {a.x,a.y,a.z,a.w};
            #pragma unroll
            for (int i = 0; i < 4; ++i)
                #pragma unroll
                for (int j = 0; j < 8; ++j)
                    acc1[i][j] = fmaf(av[i], wv[j], acc1[i][j]);
        }
        float4 bA = *(const float4*)&b1[j0];
        float4 bB = *(const float4*)&b1[j0+4];
        float bv[8] = {bA.x,bA.y,bA.z,bA.w,bB.x,bB.y,bB.z,bB.w};
        int swz = jg & 7;
        #pragma unroll
        for (int jj = 0; jj < 8; ++jj) {
            float4 hv;
            float h;
            h = acc1[0][jj] + bv[jj]; hv.x = 0.5f*h*(1.f+erff(h*0.70710678f));
            h = acc1[1][jj] + bv[jj]; hv.y = 0.5f*h*(1.f+erff(h*0.70710678f));
            h = acc1[2][jj] + bv[jj]; hv.z = 0.5f*h*(1.f+erff(h*0.70710678f));
            h = acc1[3][jj] + bv[jj]; hv.w = 0.5f*h*(1.f+erff(h*0.70710678f));
            int chunk = (t0 >> 2) ^ swz;
            *(float4*)&lh[(j0+jj)*32 + chunk*4] = hv;
        }
    }
    __syncthreads();

    // ---- GEMM2: [32 x 384] @ [384 x 96], k split 4 ways
    int kq = tid / 96;
    int r  = tid % 96;
    int cg = r / 8, tg2 = r % 8;
    int c0 = cg*8, t0b = tg2*4;
    float acc2[4][8] = {};
    for (int kk = 0; kk < 96; ++kk) {
        int k = kq*96 + kk;
        int chunk = (t0b >> 2) ^ ((k >> 3) & 7);
        float4 hv = *(const float4*)&lh[k*32 + chunk*4];
        float4 wA = *(const float4*)&w2[(size_t)k*CC_ + c0];
        float4 wB = *(const float4*)&w2[(size_t)k*CC_ + c0 + 4];
        float wv[8] = {wA.x,wA.y,wA.z,wA.w,wB.x,wB.y,wB.z,wB.w};
        float av[4] = {hv.x,hv.y,hv.z,hv.w};
        #pragma unroll
        for (int i = 0; i < 4; ++i)
            #pragma unroll
            for (int cc = 0; cc < 8; ++cc)
                acc2[i][cc] = fmaf(av[i], wv[cc], acc2[i][cc]);
    }
    __syncthreads();   // all reads of lh done; reuse as partial buffer [kq][t][c]
    #pragma unroll
    for (int i = 0; i < 4; ++i) {
        float4 pA = {acc2[i][0],acc2[i][1],acc2[i][2],acc2[i][3]};
        float4 pB = {acc2[i][4],acc2[i][5],acc2[i][6],acc2[i][7]};
        *(float4*)&lh[(kq*32 + t0b + i)*CC_ + c0]     = pA;
        *(float4*)&lh[(kq*32 + t0b + i)*CC_ + c0 + 4] = pB;
    }
    __syncthreads();

    // ---- reduce 4 partials + bias, accumulate into out
    {
        int c  = tid % CC_;
        int tq = tid / CC_;               // 0..3 -> tokens tq*8..+7
        float bc = b2[c];
        size_t obase = ((size_t)n*CC_ + c)*HWHW + hw0 + tq*8;
        float4 o0 = *(const float4*)(out + obase);
        float4 o1 = *(const float4*)(out + obase + 4);
        float vsum[8];
        #pragma unroll
        for (int tt = 0; tt < 8; ++tt) {
            int t = tq*8 + tt;
            vsum[tt] = lh[(0*32+t)*CC_+c] + lh[(1*32+t)*CC_+c]
                     + lh[(2*32+t)*CC_+c] + lh[(3*32+t)*CC_+c] + bc;
        }
        o0.x += vsum[0]; o0.y += vsum[1]; o0.z += vsum[2]; o0.w += vsum[3];
        o1.x += vsum[4]; o1.y += vsum[5]; o1.z += vsum[6]; o1.w += vsum[7];
        *(float4*)(out + obase)     = o0;
        *(float4*)(out + obase + 4) = o1;
    }
}

// ---------------------------------------------------------------------------
extern "C" void kernel_launch(void* const* d_in, const int* in_sizes, int n_in,
                              void* d_out, int out_size, void* d_ws, size_t ws_size,
                              hipStream_t stream) {
    const float* x    = (const float*)d_in[0];
    const float* ln1w = (const float*)d_in[1];
    const float* ln1b = (const float*)d_in[2];
    const float* wnn  = (const float*)d_in[3];
    const float* ln2w = (const float*)d_in[4];
    const float* ln2b = (const float*)d_in[5];
    const float* w1   = (const float*)d_in[6];
    const float* b1   = (const float*)d_in[7];
    const float* w2   = (const float*)d_in[8];
    const float* b2   = (const float*)d_in[9];
    float* out = (float*)d_out;
    float* ws  = (float*)d_ws;

    float* Wf = ws;                       // 21504
    float* Wt = Wf + WTOTAL;              // 21504
    float* X  = Wt + WTOTAL;              // NELEM
    float* Hu = X  + NELEM;               // NELEM
    float* R  = Hu + NELEM;               // NELEM (ratio, later XLN)
    float* S0 = R  + NELEM;               // NPIX
    float* S1 = S0 + NPIX;                // NPIX

    wnorm2_kernel<<<CC_, 256, 0, stream>>>(wnn, Wf, Wt);
    ln1_kernel<<<NPIX/256, 256, 0, stream>>>(x, ln1w, ln1b, X);
    fill_kernel<<<NELEM/256, 256, 0, stream>>>(Hu, NELEM, 1.f/CC_);
    fill_kernel<<<NPIX/256, 256, 0, stream>>>(S0, NPIX, 1.f);

    for (int it = 0; it < NITER; ++it) {
        float* Scur = (it & 1) ? S1 : S0;
        float* Snxt = (it & 1) ? S0 : S1;
        // R = X / (convT(Hu/S) + EPS); also zeroes Snxt
        conv4_kernel<0><<<448, 256, 0, stream>>>(Hu, Wt, X, Scur, Snxt, nullptr, R);
        // Hu = (Hu/S) * conv(R); Snxt += channel sums
        conv4_kernel<1><<<448, 256, 0, stream>>>(R, Wf, nullptr, Scur, Snxt, Hu, nullptr);
    }
    float* Sfin = S1;  // 25 iters: last writes S1

    resln2_kernel<<<NPIX/256, 256, 0, stream>>>(x, Hu, Sfin, ln2w, ln2b, out, R);
    mlp3_kernel<<<NPIX/32, 384, 0, stream>>>(R, w1, b1, w2, b2, out);
}